// Round 1
// baseline (633.375 us; speedup 1.0000x reference)
//
#include <hip/hip_runtime.h>
#include <hip/hip_bf16.h>
#include <math.h>

// Dims (fixed by the problem)
#define Bd 32
#define Sd 256
#define Ld 24
#define Ed 300
#define Hd 256
#define Td 16
#define Dd 256
#define EP 320    // E padded to multiple of 32

using short8 = __attribute__((ext_vector_type(8))) short;
using f32x4  = __attribute__((ext_vector_type(4))) float;

// fast transcendentals (v_exp_f32 path; saturate correctly at +-inf)
__device__ __forceinline__ float fsigm(float x) { return 1.f / (1.f + __expf(-x)); }
__device__ __forceinline__ float ftanh(float x) {
  float e = __expf(2.f * x);
  return 1.f - 2.f / (e + 1.f);
}

// ---------------------------------------------------------------------------
// 1. sentence means: A_pad[r][k] = bf16(mean_w emb[word_ids[r][w]][k]), k<300, else 0
// grid 8192, block 320. emb is FLOAT32.
__global__ void sent_means_kernel(const int* __restrict__ wids,
                                  const float* __restrict__ emb,
                                  __hip_bfloat16* __restrict__ apad) {
  int r = blockIdx.x;
  __shared__ int ids[Ld];
  int tid = threadIdx.x;
  if (tid < Ld) ids[tid] = wids[r * Ld + tid];
  __syncthreads();
  float acc = 0.f;
  if (tid < Ed) {
#pragma unroll
    for (int w = 0; w < Ld; ++w) acc += emb[(size_t)ids[w] * Ed + tid];
    acc *= (1.f / 24.f);
  }
  apad[r * EP + tid] = __float2bfloat16(tid < Ed ? acc : 0.f);
}

// ---------------------------------------------------------------------------
// 2. fused GRU-weight prep (fp32 -> bf16): pad_wih f+b, whh f2bf f+b.
// grid 1728, block 512; total 884736 elements.
__global__ void prep1_kernel(const float* __restrict__ wih_f, const float* __restrict__ wih_b,
                             const float* __restrict__ whh_f, const float* __restrict__ whh_b,
                             __hip_bfloat16* __restrict__ wpadf, __hip_bfloat16* __restrict__ wpadb,
                             __hip_bfloat16* __restrict__ whhbf_f, __hip_bfloat16* __restrict__ whhbf_b) {
  int i = blockIdx.x * 512 + threadIdx.x;
  const int PW = 768 * EP;     // 245760
  const int WH = 768 * Hd;     // 196608
  if (i < 2 * PW) {
    const float* src = (i < PW) ? wih_f : wih_b;
    __hip_bfloat16* dst = (i < PW) ? wpadf : wpadb;
    int j = (i < PW) ? i : i - PW;
    int n = j / EP, k = j % EP;
    dst[j] = __float2bfloat16(k < Ed ? src[n * Ed + k] : 0.f);
  } else {
    int j = i - 2 * PW;
    const float* src = (j < WH) ? whh_f : whh_b;
    __hip_bfloat16* dst = (j < WH) ? whhbf_f : whhbf_b;
    int k = (j < WH) ? j : j - WH;
    dst[k] = __float2bfloat16(src[k]);
  }
}

// ---------------------------------------------------------------------------
// 3. MFMA GEMM: C[M,N] = A[M,K] @ W[N,K]^T (+bias[n]); A,W bf16 row-major, C fp32.
__global__ __launch_bounds__(256) void gemm_xwt_kernel(
    const __hip_bfloat16* __restrict__ A, int lda,
    const __hip_bfloat16* __restrict__ W, int ldw,
    float* __restrict__ C, int ldc,
    int M, int N, int K,
    const float* __restrict__ bias) {
  __shared__ unsigned short la[64][32];
  __shared__ unsigned short lb[64][32];
  const int tid = threadIdx.x;
  const int m0 = blockIdx.x * 64, n0 = blockIdx.y * 64;
  const int lane = tid & 63, wid = tid >> 6;
  const int wm = (wid >> 1) * 32, wn = (wid & 1) * 32;
  const int lrow = tid >> 2, lcol = (tid & 3) * 8;
  f32x4 acc00 = {0.f, 0.f, 0.f, 0.f}, acc01 = {0.f, 0.f, 0.f, 0.f};
  f32x4 acc10 = {0.f, 0.f, 0.f, 0.f}, acc11 = {0.f, 0.f, 0.f, 0.f};
  int arow = m0 + lrow; if (arow > M - 1) arow = M - 1;
  const int brow = n0 + lrow;
  const int fr = lane & 15, fq = (lane >> 4) * 8;
  for (int k0 = 0; k0 < K; k0 += 32) {
    uint4 av = *(const uint4*)(A + (size_t)arow * lda + k0 + lcol);
    uint4 bv = *(const uint4*)(W + (size_t)brow * ldw + k0 + lcol);
    *(uint4*)(&la[lrow][lcol]) = av;
    *(uint4*)(&lb[lrow][lcol]) = bv;
    __syncthreads();
    short8 a0 = *(const short8*)(&la[wm + fr][fq]);
    short8 a1 = *(const short8*)(&la[wm + 16 + fr][fq]);
    short8 b0 = *(const short8*)(&lb[wn + fr][fq]);
    short8 b1 = *(const short8*)(&lb[wn + 16 + fr][fq]);
    acc00 = __builtin_amdgcn_mfma_f32_16x16x32_bf16(a0, b0, acc00, 0, 0, 0);
    acc01 = __builtin_amdgcn_mfma_f32_16x16x32_bf16(a0, b1, acc01, 0, 0, 0);
    acc10 = __builtin_amdgcn_mfma_f32_16x16x32_bf16(a1, b0, acc10, 0, 0, 0);
    acc11 = __builtin_amdgcn_mfma_f32_16x16x32_bf16(a1, b1, acc11, 0, 0, 0);
    __syncthreads();
  }
  const int rq = (lane >> 4) * 4;
  f32x4 accs[2][2] = {{acc00, acc01}, {acc10, acc11}};
  for (int i = 0; i < 2; ++i)
    for (int j = 0; j < 2; ++j) {
      int n = n0 + wn + j * 16 + fr;
      float bv = bias ? bias[n] : 0.f;
      for (int r2 = 0; r2 < 4; ++r2) {
        int m = m0 + wm + i * 16 + rq + r2;
        if (m < M) C[(size_t)m * ldc + n] = accs[i][j][r2] + bv;
      }
    }
}

// ---------------------------------------------------------------------------
// 4. Persistent-weight MFMA GRU v2 with FUSED attention-weight packing on
// otherwise-idle CUs.
//
// v2 restructure (theory: per-step critical path was ~3125cy vs the ~1860cy
// per-CU MFMA-pipe floor of the 768x256 matvec; the ~1260cy excess was
// barrier drains + gh LDS round-trip + reg-staged burst):
//  - wave-local gates: wave w owns j in [32w,32w+32) for ALL 3 gates
//    (6 n-tiles r/z/n x 2 halves) -> elementwise is in-wave, gh buffer and
//    one barrier per step deleted.
//  - h double-buffered -> exactly ONE barrier per step.
//  - raw s_barrier + lgkmcnt(0) only; vmcnt(0) only at t%8==7 (prefetch
//    issued 7 steps earlier, stores 8 steps earlier -> fully hidden).
//  - gi prefetch via global_load_lds width=16 (LDS dest linear in lane
//    order: per-wave base + lane*16), no VGPR round-trip, no in-step stall.
//
// Blocks [0,64): GRU recurrence (dir=blk>>5, b=blk&31), block 512.
// Blocks [64,384): build Wpack1/Wpack2 bf16 [1280][512] while the GRU runs.
__global__ __launch_bounds__(512, 2) void gru_mfma_kernel(
    const float* __restrict__ gi_f, const float* __restrict__ gi_b,
    const __hip_bfloat16* __restrict__ whhbf_f, const __hip_bfloat16* __restrict__ whhbf_b,
    const float* __restrict__ bhh_f, const float* __restrict__ bhh_b,
    float* __restrict__ sent_rep, __hip_bfloat16* __restrict__ sent_rep_bf,
    float* __restrict__ hT_f, float* __restrict__ hT_b,
    const float* __restrict__ w_att, const float* __restrict__ w_dna,
    __hip_bfloat16* __restrict__ wpack1, __hip_bfloat16* __restrict__ wpack2) {
  __shared__ float gi_lds[2][8][768];          // 49152 B (flat, lane-linear for global_load_lds)
  __shared__ __hip_bfloat16 h_bf[2][256];      // 1024 B double-buffered h
  __shared__ float stg32[8][256];              // 8192 B store staging
  const int blk = blockIdx.x;
  const int tid = threadIdx.x;

  if (blk >= 64) {
    // ---- fused weight-pack branch (no barriers, no LDS) ----
    const size_t q = (size_t)(blk - 64) * 512 + tid;
    size_t flat = q * 8;                        // [0, 1310720)
    const size_t HALF = (size_t)1280 * 512;     // 655360
    const bool second = flat >= HALF;
    size_t r = second ? flat - HALF : flat;
    int n = (int)(r >> 9), k0 = (int)(r & 511);
    __hip_bfloat16* dst = second ? wpack2 : wpack1;
#pragma unroll
    for (int j = 0; j < 8; ++j) {
      int k = k0 + j;
      float v;
      if (!second)
        v = (n < 1024) ? w_att[(size_t)k * 1024 + n]
                       : w_dna[(size_t)(512 + k) * 256 + (n - 1024)];
      else
        v = (n < 1024) ? w_att[(size_t)(512 + k) * 1024 + n]
                       : w_dna[(size_t)k * 256 + (n - 1024)];
      dst[(size_t)n * 512 + k] = __float2bfloat16(v);
    }
    return;
  }

  // ---- GRU recurrence branch ----
  const int dir = blk >> 5, b = blk & 31;
  const int lane = tid & 63, w = tid >> 6;
  const float* gi = dir ? gi_b : gi_f;
  const __hip_bfloat16* whh = dir ? whhbf_b : whhbf_f;
  const float* bhh = dir ? bhh_b : bhh_f;

  const int fr = lane & 15;            // fragment row (B) / output col (D)
  const int kq = (lane >> 4) * 8;      // k sub-offset within 32-chunk

  // prefetch first gi tile directly into LDS (width-16 global_load_lds;
  // dest = wave-uniform base + lane*16 since idx is thread-linear)
  auto burst = [&](int tstart, int buf) {
#pragma unroll
    for (int i = 0; i < 3; ++i) {
      int idx = tid + i * 512;               // 0..1535 = 8 rows x 192 float4
      int u = idx / 192;
      int c4 = (idx - u * 192) * 4;
      int s = dir ? (255 - (tstart + u)) : (tstart + u);
      const float* g = gi + (size_t)(((b << 8) + s) * 768 + c4);
      float* l = &gi_lds[buf][u][c4];
      __builtin_amdgcn_global_load_lds(
          (const __attribute__((address_space(1))) unsigned int*)g,
          (__attribute__((address_space(3))) unsigned int*)l, 16, 0, 0);
    }
  };
  burst(0, 0);

  if (tid < 256) h_bf[0][tid] = __float2bfloat16(0.f);

  // wave-local gate fragments: nt = g*2+half, Whh row = g*256 + w*32 + half*16 + fr
  short8 bfrag[6][8];
  {
#pragma unroll
    for (int g = 0; g < 3; ++g)
#pragma unroll
      for (int half = 0; half < 2; ++half)
#pragma unroll
        for (int kt = 0; kt < 8; ++kt)
          bfrag[g * 2 + half][kt] =
              *(const short8*)(whh + (size_t)(g * 256 + w * 32 + half * 16 + fr) * 256 +
                               kt * 32 + kq);
  }

  // per-lane GRU state (lanes 0-15 of each wave own j1=w*32+lane, j2=j1+16)
  const int j1 = w * 32 + lane;        // only meaningful for lane<16
  const int j2 = j1 + 16;
  float bhr1 = 0.f, bhz1 = 0.f, bhn1 = 0.f, hp1 = 0.f;
  float bhr2 = 0.f, bhz2 = 0.f, bhn2 = 0.f, hp2 = 0.f;
  if (lane < 16) {
    bhr1 = bhh[j1]; bhz1 = bhh[256 + j1]; bhn1 = bhh[512 + j1];
    bhr2 = bhh[j2]; bhz2 = bhh[256 + j2]; bhn2 = bhh[512 + j2];
  }

  // prologue: wait prefetch + h init, then converge
  asm volatile("s_waitcnt vmcnt(0) lgkmcnt(0)\n\ts_barrier" ::: "memory");

  for (int t = 0; t < Sd; ++t) {
    if ((t & 7) == 0 && t + 8 < Sd) burst(t + 8, ((t >> 3) + 1) & 1);
    const int rb = t & 1, wb = rb ^ 1;

    f32x4 acc[6];
#pragma unroll
    for (int nt = 0; nt < 6; ++nt) acc[nt] = (f32x4){0.f, 0.f, 0.f, 0.f};
#pragma unroll
    for (int kt = 0; kt < 8; ++kt) {
      // broadcast h chunk; rows 1-15 of A replicate row 0 (harmless: only D row0 read)
      short8 av = *(const short8*)(&h_bf[rb][kt * 32 + kq]);
#pragma unroll
      for (int nt = 0; nt < 6; ++nt)
        acc[nt] = __builtin_amdgcn_mfma_f32_16x16x32_bf16(av, bfrag[nt][kt], acc[nt], 0, 0, 0);
    }

    if (lane < 16) {
      const float* gl = gi_lds[(t >> 3) & 1][t & 7];
      // half 0 -> j1
      float r1 = fsigm(gl[j1] + acc[0][0] + bhr1);
      float z1 = fsigm(gl[256 + j1] + acc[2][0] + bhz1);
      float n1 = ftanh(gl[512 + j1] + r1 * (acc[4][0] + bhn1));
      float h1 = (1.f - z1) * n1 + z1 * hp1;
      hp1 = h1;
      // half 1 -> j2
      float r2 = fsigm(gl[j2] + acc[1][0] + bhr2);
      float z2 = fsigm(gl[256 + j2] + acc[3][0] + bhz2);
      float n2 = ftanh(gl[512 + j2] + r2 * (acc[5][0] + bhn2));
      float h2 = (1.f - z2) * n2 + z2 * hp2;
      hp2 = h2;
      h_bf[wb][j1] = __float2bfloat16(h1);
      h_bf[wb][j2] = __float2bfloat16(h2);
      stg32[t & 7][j1] = h1;
      stg32[t & 7][j2] = h2;
    }

    if ((t & 7) == 7) {
      // drain: prefetch issued at t-7 (fully hidden) + stores issued at t-8
      asm volatile("s_waitcnt vmcnt(0) lgkmcnt(0)\n\ts_barrier" ::: "memory");
      const int base = t - 7;
#pragma unroll
      for (int i = 0; i < 4; ++i) {
        int idx = tid + i * 512;
        int u = idx >> 8, d = idx & 255;
        int sg = dir ? (255 - (base + u)) : (base + u);
        size_t rowg = (size_t)((b << 8) + sg);
        int col = dir ? (256 + d) : d;
        float v = stg32[u][d];
        sent_rep[rowg * 512 + col] = v;
        sent_rep_bf[rowg * 512 + col] = __float2bfloat16(v);
      }
      // converge before next step overwrites stg32 row 0 (stores stay in flight)
      asm volatile("s_waitcnt lgkmcnt(0)\n\ts_barrier" ::: "memory");
    } else {
      asm volatile("s_waitcnt lgkmcnt(0)\n\ts_barrier" ::: "memory");
    }
  }
  if (lane < 16) {
    float* hT = dir ? hT_b : hT_f;
    hT[b * 256 + j1] = hp1;
    hT[b * 256 + j2] = hp2;
  }
}

// ---------------------------------------------------------------------------
// 5. doc_vec per torch view(B,2H) on stacked [2,B,H]. grid 32, block 512.
__global__ void docvec_kernel(const float* __restrict__ hTf, const float* __restrict__ hTb,
                              __hip_bfloat16* __restrict__ dv) {
  int b = blockIdx.x, jj = threadIdx.x;
  int idx = b * 512 + jj;
  int dsel = idx >> 13;            // /8192
  int rem = idx & 8191;
  int bp = rem >> 8, hp = rem & 255;
  float v = (dsel ? hTb : hTf)[bp * Hd + hp];
  dv[idx] = __float2bfloat16(v);
}

// 6. topic_mat via boundary differencing. grid 512 (b*16+t), block 256.
__global__ void topic_kernel(const int* __restrict__ tse, const float* __restrict__ sent_rep,
                             __hip_bfloat16* __restrict__ topic_bf) {
  int bt = blockIdx.x;
  int b = bt >> 4;
  int st = tse[bt * 2], en = tse[bt * 2 + 1];   // 1-indexed
  int dd = threadIdx.x;
  auto pad = [&](int i, int col) -> float {
    if (i < 1 || i > Sd) return 0.f;
    return sent_rep[((size_t)((b << 8) + (i - 1))) * 512 + col];
  };
  float fwd = pad(en, dd) - pad(st - 1, dd);
  float bwd = pad(st, Hd + dd) - pad(en + 1, Hd + dd);
  topic_bf[(size_t)bt * 512 + dd] = __float2bfloat16(fwd);
  topic_bf[(size_t)bt * 512 + Hd + dd] = __float2bfloat16(bwd);
}

// ---------------------------------------------------------------------------
// 7. attention scores. grid 8192 (b*256+s), block 256.
// QU rows are 1280 wide (Q = cols 0..1023); PD/RT rows 1280 (P/R = cols 0..1023).
__global__ void scores_kernel(const float* __restrict__ PD, const float* __restrict__ RT,
                              const float* __restrict__ QU, const float* __restrict__ v_att,
                              const int* __restrict__ tse,
                              float* __restrict__ dsc, float* __restrict__ tsc) {
  int r = blockIdx.x;
  int b = r >> 8, s = r & 255;
  int tid = threadIdx.x;
  int tsel = Td - 1;
  for (int t = 0; t < Td; ++t) {
    if (tse[(b * Td + t) * 2 + 1] >= s + 1) { tsel = t; break; }
  }
  const float* q = QU + (size_t)r * 1280;
  const float* p = PD + (size_t)b * 1280;
  const float* rr = RT + (size_t)(b * Td + tsel) * 1280;
  float accd = 0.f, acct = 0.f;
  for (int n = tid; n < 1024; n += 256) {
    float qv = q[n];
    float vv = v_att[n];
    accd += ftanh(p[n] + qv) * vv;
    acct += ftanh(rr[n] + qv) * vv;
  }
  __shared__ float s1[256], s2[256];
  s1[tid] = accd; s2[tid] = acct;
  __syncthreads();
  for (int off = 128; off > 0; off >>= 1) {
    if (tid < off) { s1[tid] += s1[tid + off]; s2[tid] += s2[tid + off]; }
    __syncthreads();
  }
  if (tid == 0) { dsc[r] = s1[0]; tsc[r] = s2[0]; }
}

// 8. softmax over s per batch (both score sets). grid 32, block 256.
__global__ void softmax_kernel(const float* __restrict__ dsc, const float* __restrict__ tsc,
                               float* __restrict__ dw, float* __restrict__ tw) {
  int b = blockIdx.x, s = threadIdx.x;
  __shared__ float red[256];
  for (int which = 0; which < 2; ++which) {
    const float* src = which ? tsc : dsc;
    float v = src[b * Sd + s];
    red[s] = v; __syncthreads();
    for (int off = 128; off > 0; off >>= 1) {
      if (s < off) red[s] = fmaxf(red[s], red[s + off]);
      __syncthreads();
    }
    float m = red[0]; __syncthreads();
    float e = __expf(v - m);
    red[s] = e; __syncthreads();
    for (int off = 128; off > 0; off >>= 1) {
      if (s < off) red[s] += red[s + off];
      __syncthreads();
    }
    float sum = red[0]; __syncthreads();
    (which ? tw : dw)[b * Sd + s] = e / sum;
  }
}

// 9. final head. grid 8192, block 256. OUTPUT IS FP32.
// U = QU cols 1024..1279; dvd = PD cols 1024..1279; tvd = RT cols 1024..1279.
__global__ void final_kernel(const float* __restrict__ QU, const float* __restrict__ PD,
                             const float* __restrict__ RT, const float* __restrict__ dw,
                             const float* __restrict__ tw, const float* __restrict__ b_dna,
                             const float* __restrict__ w_out,
                             const float* __restrict__ b_out,
                             const int* __restrict__ tse, float* __restrict__ out) {
  int r = blockIdx.x;
  int b = r >> 8, s = r & 255;
  int dd = threadIdx.x;
  int tsel = Td - 1;
  for (int t = 0; t < Td; ++t) {
    if (tse[(b * Td + t) * 2 + 1] >= s + 1) { tsel = t; break; }
  }
  float wdv = dw[b * Sd + s], wtv = tw[b * Sd + s];
  float x = QU[(size_t)r * 1280 + 1024 + dd] + wdv * PD[(size_t)b * 1280 + 1024 + dd] +
            wtv * RT[(size_t)(b * Td + tsel) * 1280 + 1024 + dd] + b_dna[dd];
  x = fmaxf(x, 0.f);
  float term = x * w_out[dd];
  __shared__ float red[256];
  red[dd] = term; __syncthreads();
  for (int off = 128; off > 0; off >>= 1) {
    if (dd < off) red[dd] += red[dd + off];
    __syncthreads();
  }
  if (dd == 0) out[r] = red[0] + b_out[0];
}

// ---------------------------------------------------------------------------
static void launch_gemm(const __hip_bfloat16* A, int lda, const __hip_bfloat16* W, int ldw,
                        float* C, int ldc, int M, int N, int K,
                        const float* bias, hipStream_t stream) {
  dim3 grid((M + 63) / 64, N / 64);
  gemm_xwt_kernel<<<grid, 256, 0, stream>>>(A, lda, W, ldw, C, ldc, M, N, K, bias);
}

extern "C" void kernel_launch(void* const* d_in, const int* in_sizes, int n_in,
                              void* d_out, int out_size, void* d_ws, size_t ws_size,
                              hipStream_t stream) {
  const int* word_ids = (const int*)d_in[0];
  const int* tse      = (const int*)d_in[1];
  const float* emb   = (const float*)d_in[2];
  const float* wih_f = (const float*)d_in[3];
  const float* whh_f = (const float*)d_in[4];
  const float* bih_f = (const float*)d_in[5];
  const float* bhh_f = (const float*)d_in[6];
  const float* wih_b = (const float*)d_in[7];
  const float* whh_b = (const float*)d_in[8];
  const float* bih_b = (const float*)d_in[9];
  const float* bhh_b = (const float*)d_in[10];
  const float* w_att = (const float*)d_in[11];
  const float* v_att = (const float*)d_in[12];
  const float* w_dna = (const float*)d_in[13];
  const float* b_dna = (const float*)d_in[14];
  const float* w_out = (const float*)d_in[15];
  const float* b_out = (const float*)d_in[16];
  float* out = (float*)d_out;
  char* ws = (char*)d_ws;

  const int M = Bd * Sd;  // 8192

  // workspace layout (bytes)
  size_t off = 0;
  auto alloc = [&](size_t sz) { size_t o = off; off += (sz + 255) & ~(size_t)255; return o; };
  size_t o_svbf   = alloc((size_t)M * EP * 2);          // A_pad bf16 [8192,320]
  size_t o_wpadf  = alloc((size_t)768 * EP * 2);
  size_t o_wpadb  = alloc((size_t)768 * EP * 2);
  size_t o_whhbf  = alloc((size_t)768 * Hd * 2 * 2);    // whh f+b bf16
  size_t o_wpack1 = alloc((size_t)1280 * 512 * 2);      // [W_att[:512];W_dna[512:]] ^T bf16
  size_t o_wpack2 = alloc((size_t)1280 * 512 * 2);      // [W_att[512:];W_dna[:512]] ^T bf16
  size_t o_hTf    = alloc((size_t)Bd * Hd * 4);
  size_t o_hTb    = alloc((size_t)Bd * Hd * 4);
  size_t o_dvbf   = alloc((size_t)Bd * 512 * 2);        // doc_vec bf16
  size_t o_topbf  = alloc((size_t)Bd * Td * 512 * 2);   // topic_mat bf16
  size_t o_PD     = alloc((size_t)Bd * 1280 * 4);       // [P | dvd]
  size_t o_RT     = alloc((size_t)Bd * Td * 1280 * 4);  // [R | tvd]
  size_t o_dsc    = alloc((size_t)Bd * Sd * 4);
  size_t o_tsc    = alloc((size_t)Bd * Sd * 4);
  size_t o_dw     = alloc((size_t)Bd * Sd * 4);
  size_t o_tw     = alloc((size_t)Bd * Sd * 4);
  size_t o_srep32 = alloc((size_t)M * 512 * 4);         // sent_rep fp32
  size_t o_srepbf = alloc((size_t)M * 512 * 2);         // sent_rep bf16
  size_t o_gif    = alloc((size_t)M * 768 * 4);         // gi fwd fp32
  size_t o_gib    = alloc((size_t)M * 768 * 4);         // gi bwd fp32
  // QU [8192,1280] f32 overlays the dead gi region after the GRU
  size_t o_QU = o_gif;
  (void)ws_size;

  __hip_bfloat16* svbf   = (__hip_bfloat16*)(ws + o_svbf);
  __hip_bfloat16* wpadf  = (__hip_bfloat16*)(ws + o_wpadf);
  __hip_bfloat16* wpadb  = (__hip_bfloat16*)(ws + o_wpadb);
  __hip_bfloat16* whhbf_f = (__hip_bfloat16*)(ws + o_whhbf);
  __hip_bfloat16* whhbf_b = whhbf_f + 768 * Hd;
  __hip_bfloat16* wpack1 = (__hip_bfloat16*)(ws + o_wpack1);
  __hip_bfloat16* wpack2 = (__hip_bfloat16*)(ws + o_wpack2);
  float* hTf = (float*)(ws + o_hTf);
  float* hTb = (float*)(ws + o_hTb);
  __hip_bfloat16* dvbf  = (__hip_bfloat16*)(ws + o_dvbf);
  __hip_bfloat16* topbf = (__hip_bfloat16*)(ws + o_topbf);
  float* PD  = (float*)(ws + o_PD);
  float* RT  = (float*)(ws + o_RT);
  float* dsc = (float*)(ws + o_dsc);
  float* tsc = (float*)(ws + o_tsc);
  float* dw  = (float*)(ws + o_dw);
  float* tw  = (float*)(ws + o_tw);
  float* srep32 = (float*)(ws + o_srep32);
  __hip_bfloat16* srepbf = (__hip_bfloat16*)(ws + o_srepbf);
  float* gif = (float*)(ws + o_gif);
  float* gib = (float*)(ws + o_gib);
  float* QU  = (float*)(ws + o_QU);

  // 1. sentence means -> padded bf16 activations
  sent_means_kernel<<<M, EP, 0, stream>>>(word_ids, emb, svbf);
  // 2. fused GRU weight prep
  prep1_kernel<<<1728, 512, 0, stream>>>(wih_f, wih_b, whh_f, whh_b,
                                         wpadf, wpadb, whhbf_f, whhbf_b);
  // 3. input projections gi = sv @ Wih^T + bih
  launch_gemm(svbf, EP, wpadf, EP, gif, 768, M, 768, EP, bih_f, stream);
  launch_gemm(svbf, EP, wpadb, EP, gib, 768, M, 768, EP, bih_b, stream);
  // 4. GRU recurrence + fused att/dna weight packing on idle CUs
  gru_mfma_kernel<<<384, 512, 0, stream>>>(gif, gib, whhbf_f, whhbf_b, bhh_f, bhh_b,
                                           srep32, srepbf, hTf, hTb,
                                           w_att, w_dna, wpack1, wpack2);
  // 5/6. doc_vec + topic_mat
  docvec_kernel<<<Bd, 512, 0, stream>>>(hTf, hTb, dvbf);
  topic_kernel<<<Bd * Td, 256, 0, stream>>>(tse, srep32, topbf);
  // 7. merged attention/dense GEMMs
  launch_gemm(srepbf, 512, wpack2, 512, QU, 1280, M, 1280, 512, nullptr, stream);
  launch_gemm(dvbf, 512, wpack1, 512, PD, 1280, Bd, 1280, 512, nullptr, stream);
  launch_gemm(topbf, 512, wpack1, 512, RT, 1280, Bd * Td, 1280, 512, nullptr, stream);
  // 8. scores + softmax
  scores_kernel<<<M, 256, 0, stream>>>(PD, RT, QU, v_att, tse, dsc, tsc);
  softmax_kernel<<<Bd, 256, 0, stream>>>(dsc, tsc, dw, tw);
  // 9. fused dense head -> logits (fp32)
  final_kernel<<<M, 256, 0, stream>>>(QU, PD, RT, dw, tw, b_dna, w_out, b_out, tse, out);
}

// Round 2
// 577.019 us; speedup vs baseline: 1.0977x; 1.0977x over previous
//
#include <hip/hip_runtime.h>
#include <hip/hip_bf16.h>
#include <math.h>

// Dims (fixed by the problem)
#define Bd 32
#define Sd 256
#define Ld 24
#define Ed 300
#define Hd 256
#define Td 16
#define Dd 256
#define EP 320    // E padded to multiple of 32

using short8 = __attribute__((ext_vector_type(8))) short;
using f32x4  = __attribute__((ext_vector_type(4))) float;

// fast transcendentals (v_exp_f32 path; saturate correctly at +-inf)
__device__ __forceinline__ float fsigm(float x) { return 1.f / (1.f + __expf(-x)); }
__device__ __forceinline__ float ftanh(float x) {
  float e = __expf(2.f * x);
  return 1.f - 2.f / (e + 1.f);
}

// ---------------------------------------------------------------------------
// 1. sentence means: A_pad[r][k] = bf16(mean_w emb[word_ids[r][w]][k]), k<300, else 0
// grid 8192, block 320. emb is FLOAT32.
__global__ void sent_means_kernel(const int* __restrict__ wids,
                                  const float* __restrict__ emb,
                                  __hip_bfloat16* __restrict__ apad) {
  int r = blockIdx.x;
  __shared__ int ids[Ld];
  int tid = threadIdx.x;
  if (tid < Ld) ids[tid] = wids[r * Ld + tid];
  __syncthreads();
  float acc = 0.f;
  if (tid < Ed) {
#pragma unroll
    for (int w = 0; w < Ld; ++w) acc += emb[(size_t)ids[w] * Ed + tid];
    acc *= (1.f / 24.f);
  }
  apad[r * EP + tid] = __float2bfloat16(tid < Ed ? acc : 0.f);
}

// ---------------------------------------------------------------------------
// 2. fused GRU-weight prep (fp32 -> bf16): pad_wih f+b, whh f2bf f+b.
// grid 1728, block 512; total 884736 elements.
__global__ void prep1_kernel(const float* __restrict__ wih_f, const float* __restrict__ wih_b,
                             const float* __restrict__ whh_f, const float* __restrict__ whh_b,
                             __hip_bfloat16* __restrict__ wpadf, __hip_bfloat16* __restrict__ wpadb,
                             __hip_bfloat16* __restrict__ whhbf_f, __hip_bfloat16* __restrict__ whhbf_b) {
  int i = blockIdx.x * 512 + threadIdx.x;
  const int PW = 768 * EP;     // 245760
  const int WH = 768 * Hd;     // 196608
  if (i < 2 * PW) {
    const float* src = (i < PW) ? wih_f : wih_b;
    __hip_bfloat16* dst = (i < PW) ? wpadf : wpadb;
    int j = (i < PW) ? i : i - PW;
    int n = j / EP, k = j % EP;
    dst[j] = __float2bfloat16(k < Ed ? src[n * Ed + k] : 0.f);
  } else {
    int j = i - 2 * PW;
    const float* src = (j < WH) ? whh_f : whh_b;
    __hip_bfloat16* dst = (j < WH) ? whhbf_f : whhbf_b;
    int k = (j < WH) ? j : j - WH;
    dst[k] = __float2bfloat16(src[k]);
  }
}

// ---------------------------------------------------------------------------
// 3. MFMA GEMM: C[M,N] = A[M,K] @ W[N,K]^T (+bias[n]); A,W bf16 row-major, C fp32.
__global__ __launch_bounds__(256) void gemm_xwt_kernel(
    const __hip_bfloat16* __restrict__ A, int lda,
    const __hip_bfloat16* __restrict__ W, int ldw,
    float* __restrict__ C, int ldc,
    int M, int N, int K,
    const float* __restrict__ bias) {
  __shared__ unsigned short la[64][32];
  __shared__ unsigned short lb[64][32];
  const int tid = threadIdx.x;
  const int m0 = blockIdx.x * 64, n0 = blockIdx.y * 64;
  const int lane = tid & 63, wid = tid >> 6;
  const int wm = (wid >> 1) * 32, wn = (wid & 1) * 32;
  const int lrow = tid >> 2, lcol = (tid & 3) * 8;
  f32x4 acc00 = {0.f, 0.f, 0.f, 0.f}, acc01 = {0.f, 0.f, 0.f, 0.f};
  f32x4 acc10 = {0.f, 0.f, 0.f, 0.f}, acc11 = {0.f, 0.f, 0.f, 0.f};
  int arow = m0 + lrow; if (arow > M - 1) arow = M - 1;
  const int brow = n0 + lrow;
  const int fr = lane & 15, fq = (lane >> 4) * 8;
  for (int k0 = 0; k0 < K; k0 += 32) {
    uint4 av = *(const uint4*)(A + (size_t)arow * lda + k0 + lcol);
    uint4 bv = *(const uint4*)(W + (size_t)brow * ldw + k0 + lcol);
    *(uint4*)(&la[lrow][lcol]) = av;
    *(uint4*)(&lb[lrow][lcol]) = bv;
    __syncthreads();
    short8 a0 = *(const short8*)(&la[wm + fr][fq]);
    short8 a1 = *(const short8*)(&la[wm + 16 + fr][fq]);
    short8 b0 = *(const short8*)(&lb[wn + fr][fq]);
    short8 b1 = *(const short8*)(&lb[wn + 16 + fr][fq]);
    acc00 = __builtin_amdgcn_mfma_f32_16x16x32_bf16(a0, b0, acc00, 0, 0, 0);
    acc01 = __builtin_amdgcn_mfma_f32_16x16x32_bf16(a0, b1, acc01, 0, 0, 0);
    acc10 = __builtin_amdgcn_mfma_f32_16x16x32_bf16(a1, b0, acc10, 0, 0, 0);
    acc11 = __builtin_amdgcn_mfma_f32_16x16x32_bf16(a1, b1, acc11, 0, 0, 0);
    __syncthreads();
  }
  const int rq = (lane >> 4) * 4;
  f32x4 accs[2][2] = {{acc00, acc01}, {acc10, acc11}};
  for (int i = 0; i < 2; ++i)
    for (int j = 0; j < 2; ++j) {
      int n = n0 + wn + j * 16 + fr;
      float bv = bias ? bias[n] : 0.f;
      for (int r2 = 0; r2 < 4; ++r2) {
        int m = m0 + wm + i * 16 + rq + r2;
        if (m < M) C[(size_t)m * ldc + n] = accs[i][j][r2] + bv;
      }
    }
}

// ---------------------------------------------------------------------------
// 4. Persistent-weight MFMA GRU v3 with FUSED attention-weight packing on
// otherwise-idle CUs.
//
// v3 = v1's proven handoff (gh LDS round-trip, dedicated elementwise waves
// 0-3, 2 barriers/step) plus three fixes:
//  - __launch_bounds__(512,1): only 1 GRU block/CU exists anyway; frees 256
//    arch VGPRs so bfrag (192 VGPR) stays in VGPRs -> no v_accvgpr shuttle
//    before every MFMA (the suspected ~750cy/step VALU tax at VGPR cap 128).
//  - waves 4-7 are memory waves: prefetch (global_load_lds, width 16) and
//    sent_rep store burst issued once per 8 steps, OVERLAPPED with the
//    elementwise phase (after barrier A) -> off the critical path.
//  - raw s_barrier + lgkmcnt(0) only; vmcnt(0) only on waves 4-7 at t%8==0,
//    draining 8-step-old DMA/stores (free). Stores/prefetch stay in flight
//    across barriers.
//
// Blocks [0,64): GRU recurrence (dir=blk>>5, b=blk&31), block 512.
// Blocks [64,384): build Wpack1/Wpack2 bf16 [1280][512] while the GRU runs.
__global__ __launch_bounds__(512, 1) void gru_mfma_kernel(
    const float* __restrict__ gi_f, const float* __restrict__ gi_b,
    const __hip_bfloat16* __restrict__ whhbf_f, const __hip_bfloat16* __restrict__ whhbf_b,
    const float* __restrict__ bhh_f, const float* __restrict__ bhh_b,
    float* __restrict__ sent_rep, __hip_bfloat16* __restrict__ sent_rep_bf,
    float* __restrict__ hT_f, float* __restrict__ hT_b,
    const float* __restrict__ w_att, const float* __restrict__ w_dna,
    __hip_bfloat16* __restrict__ wpack1, __hip_bfloat16* __restrict__ wpack2) {
  __shared__ float gi_lds[2][8][768];          // 49152 B (lane-linear for global_load_lds)
  __shared__ __hip_bfloat16 h_bf[2][256];      // 1024 B double-buffered h
  __shared__ float gh[768];                    // 3072 B matvec handoff
  __shared__ float stg32[2][8][256];           // 16384 B double-buffered store staging
  const int blk = blockIdx.x;
  const int tid = threadIdx.x;

  if (blk >= 64) {
    // ---- fused weight-pack branch (no barriers, no LDS) ----
    const size_t q = (size_t)(blk - 64) * 512 + tid;
    size_t flat = q * 8;                        // [0, 1310720)
    const size_t HALF = (size_t)1280 * 512;     // 655360
    const bool second = flat >= HALF;
    size_t r = second ? flat - HALF : flat;
    int n = (int)(r >> 9), k0 = (int)(r & 511);
    __hip_bfloat16* dst = second ? wpack2 : wpack1;
#pragma unroll
    for (int j = 0; j < 8; ++j) {
      int k = k0 + j;
      float v;
      if (!second)
        v = (n < 1024) ? w_att[(size_t)k * 1024 + n]
                       : w_dna[(size_t)(512 + k) * 256 + (n - 1024)];
      else
        v = (n < 1024) ? w_att[(size_t)(512 + k) * 1024 + n]
                       : w_dna[(size_t)k * 256 + (n - 1024)];
      dst[(size_t)n * 512 + k] = __float2bfloat16(v);
    }
    return;
  }

  // ---- GRU recurrence branch ----
  const int dir = blk >> 5, b = blk & 31;
  const int lane = tid & 63, w = tid >> 6;
  const float* gi = dir ? gi_b : gi_f;
  const __hip_bfloat16* whh = dir ? whhbf_b : whhbf_f;
  const float* bhh = dir ? bhh_b : bhh_f;

  // prologue: DMA tile 0 into buf 0 (512 threads x 3 x 16B)
  {
#pragma unroll
    for (int i = 0; i < 3; ++i) {
      int idx = tid + i * 512;               // 0..1535 = 8 rows x 192 float4
      int u = idx / 192;
      int c4 = (idx - u * 192) * 4;
      int s = dir ? (255 - u) : u;
      const float* g = gi + (size_t)(((b << 8) + s) * 768 + c4);
      __builtin_amdgcn_global_load_lds(
          (const __attribute__((address_space(1))) unsigned int*)g,
          (__attribute__((address_space(3))) unsigned int*)&gi_lds[0][u][c4], 16, 0, 0);
    }
  }
  if (tid < 256) h_bf[0][tid] = __float2bfloat16(0.f);

  // weight fragments: wave w covers outputs [96w, 96w+96), 6 n-tiles of 16
  const int fr = lane & 15, kq = (lane >> 4) * 8;
  short8 bfrag[6][8];
  {
    const int n0 = w * 96 + fr;
#pragma unroll
    for (int nt = 0; nt < 6; ++nt)
#pragma unroll
      for (int kt = 0; kt < 8; ++kt)
        bfrag[nt][kt] = *(const short8*)(whh + (size_t)(n0 + nt * 16) * 256 + kt * 32 + kq);
  }

  float bhr = 0.f, bhz = 0.f, bhn = 0.f, hprev = 0.f;
  if (tid < 256) { bhr = bhh[tid]; bhz = bhh[256 + tid]; bhn = bhh[512 + tid]; }

  // prologue: wait DMA + h init, then converge
  asm volatile("s_waitcnt vmcnt(0) lgkmcnt(0)\n\ts_barrier" ::: "memory");

  for (int t = 0; t < Sd; ++t) {
    const int rb = t & 1, wb = rb ^ 1;

    // --- MFMA phase (all 8 waves, 48 MFMAs each) ---
    f32x4 acc[6];
#pragma unroll
    for (int nt = 0; nt < 6; ++nt) acc[nt] = (f32x4){0.f, 0.f, 0.f, 0.f};
#pragma unroll
    for (int kt = 0; kt < 8; ++kt) {
      // broadcast h chunk; A rows 0-15 all replicate h (only D row 0 is read)
      short8 av = *(const short8*)(&h_bf[rb][kt * 32 + kq]);
#pragma unroll
      for (int nt = 0; nt < 6; ++nt)
        acc[nt] = __builtin_amdgcn_mfma_f32_16x16x32_bf16(av, bfrag[nt][kt], acc[nt], 0, 0, 0);
    }
    if (lane < 16) {
#pragma unroll
      for (int nt = 0; nt < 6; ++nt) gh[w * 96 + nt * 16 + lane] = acc[nt][0];
    }
    // memory waves: guarantee the tile this group reads (DMA'd 8 steps ago)
    // has landed, BEFORE barrier A. 8 steps in flight -> free.
    if (w >= 4 && (t & 7) == 0)
      asm volatile("s_waitcnt vmcnt(0)" ::: "memory");
    asm volatile("s_waitcnt lgkmcnt(0)\n\ts_barrier" ::: "memory");   // barrier A: gh visible

    if (tid < 256) {
      // --- elementwise waves 0-3: one h value per lane ---
      const float* gl = gi_lds[(t >> 3) & 1][t & 7];
      float rr = fsigm(gl[tid] + gh[tid] + bhr);
      float zz = fsigm(gl[256 + tid] + gh[256 + tid] + bhz);
      float nn = ftanh(gl[512 + tid] + rr * (gh[512 + tid] + bhn));
      float hn = (1.f - zz) * nn + zz * hprev;
      hprev = hn;
      h_bf[wb][tid] = __float2bfloat16(hn);
      stg32[(t >> 3) & 1][t & 7][tid] = hn;
    } else if ((t & 7) == 0) {
      // --- memory waves 4-7: overlapped with elementwise ---
      if (t + 8 < Sd) {
        // prefetch tile t+8 into the buffer NOT read this group
        const int buf = ((t >> 3) + 1) & 1;
#pragma unroll
        for (int i = 0; i < 6; ++i) {
          int idx = (tid - 256) + i * 256;   // 0..1535
          int u = idx / 192;
          int c4 = (idx - u * 192) * 4;
          int s = dir ? (255 - (t + 8 + u)) : (t + 8 + u);
          const float* g = gi + (size_t)(((b << 8) + s) * 768 + c4);
          __builtin_amdgcn_global_load_lds(
              (const __attribute__((address_space(1))) unsigned int*)g,
              (__attribute__((address_space(3))) unsigned int*)&gi_lds[buf][u][c4], 16, 0, 0);
        }
      }
      if (t >= 8) {
        // store the group finished last step (steps t-8..t-1)
        const int base = t - 8;
        const int gp = ((t >> 3) - 1) & 1;
        const int d = tid - 256;
#pragma unroll
        for (int u = 0; u < 8; ++u) {
          int sg = dir ? (255 - (base + u)) : (base + u);
          size_t rowg = (size_t)((b << 8) + sg);
          int col = dir ? (256 + d) : d;
          float v = stg32[gp][u][d];
          sent_rep[rowg * 512 + col] = v;
          sent_rep_bf[rowg * 512 + col] = __float2bfloat16(v);
        }
      }
    }
    asm volatile("s_waitcnt lgkmcnt(0)\n\ts_barrier" ::: "memory");   // barrier B: h visible
  }

  // epilogue: store last group (31, in stg32[1]) + final hidden
  if (w >= 4) {
    const int base = 248, d = tid - 256;
#pragma unroll
    for (int u = 0; u < 8; ++u) {
      int sg = dir ? (255 - (base + u)) : (base + u);
      size_t rowg = (size_t)((b << 8) + sg);
      int col = dir ? (256 + d) : d;
      float v = stg32[1][u][d];
      sent_rep[rowg * 512 + col] = v;
      sent_rep_bf[rowg * 512 + col] = __float2bfloat16(v);
    }
  } else {
    (dir ? hT_b : hT_f)[b * 256 + tid] = hprev;
  }
}

// ---------------------------------------------------------------------------
// 5. doc_vec per torch view(B,2H) on stacked [2,B,H]. grid 32, block 512.
__global__ void docvec_kernel(const float* __restrict__ hTf, const float* __restrict__ hTb,
                              __hip_bfloat16* __restrict__ dv) {
  int b = blockIdx.x, jj = threadIdx.x;
  int idx = b * 512 + jj;
  int dsel = idx >> 13;            // /8192
  int rem = idx & 8191;
  int bp = rem >> 8, hp = rem & 255;
  float v = (dsel ? hTb : hTf)[bp * Hd + hp];
  dv[idx] = __float2bfloat16(v);
}

// 6. topic_mat via boundary differencing. grid 512 (b*16+t), block 256.
__global__ void topic_kernel(const int* __restrict__ tse, const float* __restrict__ sent_rep,
                             __hip_bfloat16* __restrict__ topic_bf) {
  int bt = blockIdx.x;
  int b = bt >> 4;
  int st = tse[bt * 2], en = tse[bt * 2 + 1];   // 1-indexed
  int dd = threadIdx.x;
  auto pad = [&](int i, int col) -> float {
    if (i < 1 || i > Sd) return 0.f;
    return sent_rep[((size_t)((b << 8) + (i - 1))) * 512 + col];
  };
  float fwd = pad(en, dd) - pad(st - 1, dd);
  float bwd = pad(st, Hd + dd) - pad(en + 1, Hd + dd);
  topic_bf[(size_t)bt * 512 + dd] = __float2bfloat16(fwd);
  topic_bf[(size_t)bt * 512 + Hd + dd] = __float2bfloat16(bwd);
}

// ---------------------------------------------------------------------------
// 7. attention scores. grid 8192 (b*256+s), block 256.
// QU rows are 1280 wide (Q = cols 0..1023); PD/RT rows 1280 (P/R = cols 0..1023).
__global__ void scores_kernel(const float* __restrict__ PD, const float* __restrict__ RT,
                              const float* __restrict__ QU, const float* __restrict__ v_att,
                              const int* __restrict__ tse,
                              float* __restrict__ dsc, float* __restrict__ tsc) {
  int r = blockIdx.x;
  int b = r >> 8, s = r & 255;
  int tid = threadIdx.x;
  int tsel = Td - 1;
  for (int t = 0; t < Td; ++t) {
    if (tse[(b * Td + t) * 2 + 1] >= s + 1) { tsel = t; break; }
  }
  const float* q = QU + (size_t)r * 1280;
  const float* p = PD + (size_t)b * 1280;
  const float* rr = RT + (size_t)(b * Td + tsel) * 1280;
  float accd = 0.f, acct = 0.f;
  for (int n = tid; n < 1024; n += 256) {
    float qv = q[n];
    float vv = v_att[n];
    accd += ftanh(p[n] + qv) * vv;
    acct += ftanh(rr[n] + qv) * vv;
  }
  __shared__ float s1[256], s2[256];
  s1[tid] = accd; s2[tid] = acct;
  __syncthreads();
  for (int off = 128; off > 0; off >>= 1) {
    if (tid < off) { s1[tid] += s1[tid + off]; s2[tid] += s2[tid + off]; }
    __syncthreads();
  }
  if (tid == 0) { dsc[r] = s1[0]; tsc[r] = s2[0]; }
}

// 8. softmax over s per batch (both score sets). grid 32, block 256.
__global__ void softmax_kernel(const float* __restrict__ dsc, const float* __restrict__ tsc,
                               float* __restrict__ dw, float* __restrict__ tw) {
  int b = blockIdx.x, s = threadIdx.x;
  __shared__ float red[256];
  for (int which = 0; which < 2; ++which) {
    const float* src = which ? tsc : dsc;
    float v = src[b * Sd + s];
    red[s] = v; __syncthreads();
    for (int off = 128; off > 0; off >>= 1) {
      if (s < off) red[s] = fmaxf(red[s], red[s + off]);
      __syncthreads();
    }
    float m = red[0]; __syncthreads();
    float e = __expf(v - m);
    red[s] = e; __syncthreads();
    for (int off = 128; off > 0; off >>= 1) {
      if (s < off) red[s] += red[s + off];
      __syncthreads();
    }
    float sum = red[0]; __syncthreads();
    (which ? tw : dw)[b * Sd + s] = e / sum;
  }
}

// 9. final head. grid 8192, block 256. OUTPUT IS FP32.
// U = QU cols 1024..1279; dvd = PD cols 1024..1279; tvd = RT cols 1024..1279.
__global__ void final_kernel(const float* __restrict__ QU, const float* __restrict__ PD,
                             const float* __restrict__ RT, const float* __restrict__ dw,
                             const float* __restrict__ tw, const float* __restrict__ b_dna,
                             const float* __restrict__ w_out,
                             const float* __restrict__ b_out,
                             const int* __restrict__ tse, float* __restrict__ out) {
  int r = blockIdx.x;
  int b = r >> 8, s = r & 255;
  int dd = threadIdx.x;
  int tsel = Td - 1;
  for (int t = 0; t < Td; ++t) {
    if (tse[(b * Td + t) * 2 + 1] >= s + 1) { tsel = t; break; }
  }
  float wdv = dw[b * Sd + s], wtv = tw[b * Sd + s];
  float x = QU[(size_t)r * 1280 + 1024 + dd] + wdv * PD[(size_t)b * 1280 + 1024 + dd] +
            wtv * RT[(size_t)(b * Td + tsel) * 1280 + 1024 + dd] + b_dna[dd];
  x = fmaxf(x, 0.f);
  float term = x * w_out[dd];
  __shared__ float red[256];
  red[dd] = term; __syncthreads();
  for (int off = 128; off > 0; off >>= 1) {
    if (dd < off) red[dd] += red[dd + off];
    __syncthreads();
  }
  if (dd == 0) out[r] = red[0] + b_out[0];
}

// ---------------------------------------------------------------------------
static void launch_gemm(const __hip_bfloat16* A, int lda, const __hip_bfloat16* W, int ldw,
                        float* C, int ldc, int M, int N, int K,
                        const float* bias, hipStream_t stream) {
  dim3 grid((M + 63) / 64, N / 64);
  gemm_xwt_kernel<<<grid, 256, 0, stream>>>(A, lda, W, ldw, C, ldc, M, N, K, bias);
}

extern "C" void kernel_launch(void* const* d_in, const int* in_sizes, int n_in,
                              void* d_out, int out_size, void* d_ws, size_t ws_size,
                              hipStream_t stream) {
  const int* word_ids = (const int*)d_in[0];
  const int* tse      = (const int*)d_in[1];
  const float* emb   = (const float*)d_in[2];
  const float* wih_f = (const float*)d_in[3];
  const float* whh_f = (const float*)d_in[4];
  const float* bih_f = (const float*)d_in[5];
  const float* bhh_f = (const float*)d_in[6];
  const float* wih_b = (const float*)d_in[7];
  const float* whh_b = (const float*)d_in[8];
  const float* bih_b = (const float*)d_in[9];
  const float* bhh_b = (const float*)d_in[10];
  const float* w_att = (const float*)d_in[11];
  const float* v_att = (const float*)d_in[12];
  const float* w_dna = (const float*)d_in[13];
  const float* b_dna = (const float*)d_in[14];
  const float* w_out = (const float*)d_in[15];
  const float* b_out = (const float*)d_in[16];
  float* out = (float*)d_out;
  char* ws = (char*)d_ws;

  const int M = Bd * Sd;  // 8192

  // workspace layout (bytes)
  size_t off = 0;
  auto alloc = [&](size_t sz) { size_t o = off; off += (sz + 255) & ~(size_t)255; return o; };
  size_t o_svbf   = alloc((size_t)M * EP * 2);          // A_pad bf16 [8192,320]
  size_t o_wpadf  = alloc((size_t)768 * EP * 2);
  size_t o_wpadb  = alloc((size_t)768 * EP * 2);
  size_t o_whhbf  = alloc((size_t)768 * Hd * 2 * 2);    // whh f+b bf16
  size_t o_wpack1 = alloc((size_t)1280 * 512 * 2);      // [W_att[:512];W_dna[512:]] ^T bf16
  size_t o_wpack2 = alloc((size_t)1280 * 512 * 2);      // [W_att[512:];W_dna[:512]] ^T bf16
  size_t o_hTf    = alloc((size_t)Bd * Hd * 4);
  size_t o_hTb    = alloc((size_t)Bd * Hd * 4);
  size_t o_dvbf   = alloc((size_t)Bd * 512 * 2);        // doc_vec bf16
  size_t o_topbf  = alloc((size_t)Bd * Td * 512 * 2);   // topic_mat bf16
  size_t o_PD     = alloc((size_t)Bd * 1280 * 4);       // [P | dvd]
  size_t o_RT     = alloc((size_t)Bd * Td * 1280 * 4);  // [R | tvd]
  size_t o_dsc    = alloc((size_t)Bd * Sd * 4);
  size_t o_tsc    = alloc((size_t)Bd * Sd * 4);
  size_t o_dw     = alloc((size_t)Bd * Sd * 4);
  size_t o_tw     = alloc((size_t)Bd * Sd * 4);
  size_t o_srep32 = alloc((size_t)M * 512 * 4);         // sent_rep fp32
  size_t o_srepbf = alloc((size_t)M * 512 * 2);         // sent_rep bf16
  size_t o_gif    = alloc((size_t)M * 768 * 4);         // gi fwd fp32
  size_t o_gib    = alloc((size_t)M * 768 * 4);         // gi bwd fp32
  // QU [8192,1280] f32 overlays the dead gi region after the GRU
  size_t o_QU = o_gif;
  (void)ws_size;

  __hip_bfloat16* svbf   = (__hip_bfloat16*)(ws + o_svbf);
  __hip_bfloat16* wpadf  = (__hip_bfloat16*)(ws + o_wpadf);
  __hip_bfloat16* wpadb  = (__hip_bfloat16*)(ws + o_wpadb);
  __hip_bfloat16* whhbf_f = (__hip_bfloat16*)(ws + o_whhbf);
  __hip_bfloat16* whhbf_b = whhbf_f + 768 * Hd;
  __hip_bfloat16* wpack1 = (__hip_bfloat16*)(ws + o_wpack1);
  __hip_bfloat16* wpack2 = (__hip_bfloat16*)(ws + o_wpack2);
  float* hTf = (float*)(ws + o_hTf);
  float* hTb = (float*)(ws + o_hTb);
  __hip_bfloat16* dvbf  = (__hip_bfloat16*)(ws + o_dvbf);
  __hip_bfloat16* topbf = (__hip_bfloat16*)(ws + o_topbf);
  float* PD  = (float*)(ws + o_PD);
  float* RT  = (float*)(ws + o_RT);
  float* dsc = (float*)(ws + o_dsc);
  float* tsc = (float*)(ws + o_tsc);
  float* dw  = (float*)(ws + o_dw);
  float* tw  = (float*)(ws + o_tw);
  float* srep32 = (float*)(ws + o_srep32);
  __hip_bfloat16* srepbf = (__hip_bfloat16*)(ws + o_srepbf);
  float* gif = (float*)(ws + o_gif);
  float* gib = (float*)(ws + o_gib);
  float* QU  = (float*)(ws + o_QU);

  // 1. sentence means -> padded bf16 activations
  sent_means_kernel<<<M, EP, 0, stream>>>(word_ids, emb, svbf);
  // 2. fused GRU weight prep
  prep1_kernel<<<1728, 512, 0, stream>>>(wih_f, wih_b, whh_f, whh_b,
                                         wpadf, wpadb, whhbf_f, whhbf_b);
  // 3. input projections gi = sv @ Wih^T + bih
  launch_gemm(svbf, EP, wpadf, EP, gif, 768, M, 768, EP, bih_f, stream);
  launch_gemm(svbf, EP, wpadb, EP, gib, 768, M, 768, EP, bih_b, stream);
  // 4. GRU recurrence + fused att/dna weight packing on idle CUs
  gru_mfma_kernel<<<384, 512, 0, stream>>>(gif, gib, whhbf_f, whhbf_b, bhh_f, bhh_b,
                                           srep32, srepbf, hTf, hTb,
                                           w_att, w_dna, wpack1, wpack2);
  // 5/6. doc_vec + topic_mat
  docvec_kernel<<<Bd, 512, 0, stream>>>(hTf, hTb, dvbf);
  topic_kernel<<<Bd * Td, 256, 0, stream>>>(tse, srep32, topbf);
  // 7. merged attention/dense GEMMs
  launch_gemm(srepbf, 512, wpack2, 512, QU, 1280, M, 1280, 512, nullptr, stream);
  launch_gemm(dvbf, 512, wpack1, 512, PD, 1280, Bd, 1280, 512, nullptr, stream);
  launch_gemm(topbf, 512, wpack1, 512, RT, 1280, Bd * Td, 1280, 512, nullptr, stream);
  // 8. scores + softmax
  scores_kernel<<<M, 256, 0, stream>>>(PD, RT, QU, v_att, tse, dsc, tsc);
  softmax_kernel<<<Bd, 256, 0, stream>>>(dsc, tsc, dw, tw);
  // 9. fused dense head -> logits (fp32)
  final_kernel<<<M, 256, 0, stream>>>(QU, PD, RT, dw, tw, b_dna, w_out, b_out, tse, out);
}

// Round 3
// 575.328 us; speedup vs baseline: 1.1009x; 1.0029x over previous
//
#include <hip/hip_runtime.h>
#include <hip/hip_bf16.h>
#include <math.h>

// Dims (fixed by the problem)
#define Bd 32
#define Sd 256
#define Ld 24
#define Ed 300
#define Hd 256
#define Td 16
#define Dd 256
#define EP 320    // E padded to multiple of 32

using short8 = __attribute__((ext_vector_type(8))) short;
using f32x4  = __attribute__((ext_vector_type(4))) float;

// fast transcendentals (v_exp_f32 path; saturate correctly at +-inf)
__device__ __forceinline__ float fsigm(float x) { return 1.f / (1.f + __expf(-x)); }
__device__ __forceinline__ float ftanh(float x) {
  float e = __expf(2.f * x);
  return 1.f - 2.f / (e + 1.f);
}

// ---------------------------------------------------------------------------
// 1. sentence means: A_pad[r][k] = bf16(mean_w emb[word_ids[r][w]][k]), k<300, else 0
// grid 8192, block 320. emb is FLOAT32.
__global__ void sent_means_kernel(const int* __restrict__ wids,
                                  const float* __restrict__ emb,
                                  __hip_bfloat16* __restrict__ apad) {
  int r = blockIdx.x;
  __shared__ int ids[Ld];
  int tid = threadIdx.x;
  if (tid < Ld) ids[tid] = wids[r * Ld + tid];
  __syncthreads();
  float acc = 0.f;
  if (tid < Ed) {
#pragma unroll
    for (int w = 0; w < Ld; ++w) acc += emb[(size_t)ids[w] * Ed + tid];
    acc *= (1.f / 24.f);
  }
  apad[r * EP + tid] = __float2bfloat16(tid < Ed ? acc : 0.f);
}

// ---------------------------------------------------------------------------
// 2. fused GRU-weight prep (fp32 -> bf16): pad_wih f+b, whh f2bf f+b.
// grid 1728, block 512; total 884736 elements.
__global__ void prep1_kernel(const float* __restrict__ wih_f, const float* __restrict__ wih_b,
                             const float* __restrict__ whh_f, const float* __restrict__ whh_b,
                             __hip_bfloat16* __restrict__ wpadf, __hip_bfloat16* __restrict__ wpadb,
                             __hip_bfloat16* __restrict__ whhbf_f, __hip_bfloat16* __restrict__ whhbf_b) {
  int i = blockIdx.x * 512 + threadIdx.x;
  const int PW = 768 * EP;     // 245760
  const int WH = 768 * Hd;     // 196608
  if (i < 2 * PW) {
    const float* src = (i < PW) ? wih_f : wih_b;
    __hip_bfloat16* dst = (i < PW) ? wpadf : wpadb;
    int j = (i < PW) ? i : i - PW;
    int n = j / EP, k = j % EP;
    dst[j] = __float2bfloat16(k < Ed ? src[n * Ed + k] : 0.f);
  } else {
    int j = i - 2 * PW;
    const float* src = (j < WH) ? whh_f : whh_b;
    __hip_bfloat16* dst = (j < WH) ? whhbf_f : whhbf_b;
    int k = (j < WH) ? j : j - WH;
    dst[k] = __float2bfloat16(src[k]);
  }
}

// ---------------------------------------------------------------------------
// 3. MFMA GEMM: C[M,N] = A[M,K] @ W[N,K]^T (+bias[n]); A,W bf16 row-major, C fp32.
__global__ __launch_bounds__(256) void gemm_xwt_kernel(
    const __hip_bfloat16* __restrict__ A, int lda,
    const __hip_bfloat16* __restrict__ W, int ldw,
    float* __restrict__ C, int ldc,
    int M, int N, int K,
    const float* __restrict__ bias) {
  __shared__ unsigned short la[64][32];
  __shared__ unsigned short lb[64][32];
  const int tid = threadIdx.x;
  const int m0 = blockIdx.x * 64, n0 = blockIdx.y * 64;
  const int lane = tid & 63, wid = tid >> 6;
  const int wm = (wid >> 1) * 32, wn = (wid & 1) * 32;
  const int lrow = tid >> 2, lcol = (tid & 3) * 8;
  f32x4 acc00 = {0.f, 0.f, 0.f, 0.f}, acc01 = {0.f, 0.f, 0.f, 0.f};
  f32x4 acc10 = {0.f, 0.f, 0.f, 0.f}, acc11 = {0.f, 0.f, 0.f, 0.f};
  int arow = m0 + lrow; if (arow > M - 1) arow = M - 1;
  const int brow = n0 + lrow;
  const int fr = lane & 15, fq = (lane >> 4) * 8;
  for (int k0 = 0; k0 < K; k0 += 32) {
    uint4 av = *(const uint4*)(A + (size_t)arow * lda + k0 + lcol);
    uint4 bv = *(const uint4*)(W + (size_t)brow * ldw + k0 + lcol);
    *(uint4*)(&la[lrow][lcol]) = av;
    *(uint4*)(&lb[lrow][lcol]) = bv;
    __syncthreads();
    short8 a0 = *(const short8*)(&la[wm + fr][fq]);
    short8 a1 = *(const short8*)(&la[wm + 16 + fr][fq]);
    short8 b0 = *(const short8*)(&lb[wn + fr][fq]);
    short8 b1 = *(const short8*)(&lb[wn + 16 + fr][fq]);
    acc00 = __builtin_amdgcn_mfma_f32_16x16x32_bf16(a0, b0, acc00, 0, 0, 0);
    acc01 = __builtin_amdgcn_mfma_f32_16x16x32_bf16(a0, b1, acc01, 0, 0, 0);
    acc10 = __builtin_amdgcn_mfma_f32_16x16x32_bf16(a1, b0, acc10, 0, 0, 0);
    acc11 = __builtin_amdgcn_mfma_f32_16x16x32_bf16(a1, b1, acc11, 0, 0, 0);
    __syncthreads();
  }
  const int rq = (lane >> 4) * 4;
  f32x4 accs[2][2] = {{acc00, acc01}, {acc10, acc11}};
  for (int i = 0; i < 2; ++i)
    for (int j = 0; j < 2; ++j) {
      int n = n0 + wn + j * 16 + fr;
      float bv = bias ? bias[n] : 0.f;
      for (int r2 = 0; r2 < 4; ++r2) {
        int m = m0 + wm + i * 16 + rq + r2;
        if (m < M) C[(size_t)m * ldc + n] = accs[i][j][r2] + bv;
      }
    }
}

// ---------------------------------------------------------------------------
// 4. Persistent-weight MFMA GRU v4.
//
// v1/v2/v3 all pinned at ~3100cy/step while per-CU MFMA-busy is only ~1520cy
// (MfmaUtil 12.2% x 4) vs the 1862cy pipe need -> the matrix pipe idles ~45%
// DURING the MFMA phase. Theory: in-order wave issue + compiler emitting the
// 6 accumulator chains serially (8 dependent MFMAs back-to-back) stalls each
// wave on dep latency; at 2 waves/SIMD (register file is full: weights =
// 384KB of the 512KB file) the pipe starves. v4 fixes ISSUE ORDER, not
// structure:
//  - sched_group_barrier {DS_READ x1, MFMA x6} per kt group: consecutive
//    MFMAs are independent chains; dep gap becomes 6 issue slots >> latency.
//  - gi_lds reads preloaded at step top (buffer stable since prev barrier),
//    removing ~120cy ds latency from the serial elementwise path.
//  - prefetch-consumer vmcnt(0) moved from t%8==0 to t%8==7 (pre-barrier-B),
//    making the preload safe and keeping the wait off the critical path.
//
// Blocks [0,64): GRU recurrence (dir=blk>>5, b=blk&31), block 512.
// Blocks [64,384): build Wpack1/Wpack2 bf16 [1280][512] while the GRU runs.
__global__ __launch_bounds__(512, 1) void gru_mfma_kernel(
    const float* __restrict__ gi_f, const float* __restrict__ gi_b,
    const __hip_bfloat16* __restrict__ whhbf_f, const __hip_bfloat16* __restrict__ whhbf_b,
    const float* __restrict__ bhh_f, const float* __restrict__ bhh_b,
    float* __restrict__ sent_rep, __hip_bfloat16* __restrict__ sent_rep_bf,
    float* __restrict__ hT_f, float* __restrict__ hT_b,
    const float* __restrict__ w_att, const float* __restrict__ w_dna,
    __hip_bfloat16* __restrict__ wpack1, __hip_bfloat16* __restrict__ wpack2) {
  __shared__ float gi_lds[2][8][768];          // 49152 B (lane-linear for global_load_lds)
  __shared__ __hip_bfloat16 h_bf[2][256];      // 1024 B double-buffered h
  __shared__ float gh[768];                    // 3072 B matvec handoff
  __shared__ float stg32[2][8][256];           // 16384 B double-buffered store staging
  const int blk = blockIdx.x;
  const int tid = threadIdx.x;

  if (blk >= 64) {
    // ---- fused weight-pack branch (no barriers, no LDS) ----
    const size_t q = (size_t)(blk - 64) * 512 + tid;
    size_t flat = q * 8;                        // [0, 1310720)
    const size_t HALF = (size_t)1280 * 512;     // 655360
    const bool second = flat >= HALF;
    size_t r = second ? flat - HALF : flat;
    int n = (int)(r >> 9), k0 = (int)(r & 511);
    __hip_bfloat16* dst = second ? wpack2 : wpack1;
#pragma unroll
    for (int j = 0; j < 8; ++j) {
      int k = k0 + j;
      float v;
      if (!second)
        v = (n < 1024) ? w_att[(size_t)k * 1024 + n]
                       : w_dna[(size_t)(512 + k) * 256 + (n - 1024)];
      else
        v = (n < 1024) ? w_att[(size_t)(512 + k) * 1024 + n]
                       : w_dna[(size_t)k * 256 + (n - 1024)];
      dst[(size_t)n * 512 + k] = __float2bfloat16(v);
    }
    return;
  }

  // ---- GRU recurrence branch ----
  const int dir = blk >> 5, b = blk & 31;
  const int lane = tid & 63, w = tid >> 6;
  const float* gi = dir ? gi_b : gi_f;
  const __hip_bfloat16* whh = dir ? whhbf_b : whhbf_f;
  const float* bhh = dir ? bhh_b : bhh_f;

  // prologue: DMA tile 0 into buf 0 (512 threads x 3 x 16B)
  {
#pragma unroll
    for (int i = 0; i < 3; ++i) {
      int idx = tid + i * 512;               // 0..1535 = 8 rows x 192 float4
      int u = idx / 192;
      int c4 = (idx - u * 192) * 4;
      int s = dir ? (255 - u) : u;
      const float* g = gi + (size_t)(((b << 8) + s) * 768 + c4);
      __builtin_amdgcn_global_load_lds(
          (const __attribute__((address_space(1))) unsigned int*)g,
          (__attribute__((address_space(3))) unsigned int*)&gi_lds[0][u][c4], 16, 0, 0);
    }
  }
  if (tid < 256) h_bf[0][tid] = __float2bfloat16(0.f);

  // weight fragments: wave w covers outputs [96w, 96w+96), 6 n-tiles of 16
  const int fr = lane & 15, kq = (lane >> 4) * 8;
  short8 bfrag[6][8];
  {
    const int n0 = w * 96 + fr;
#pragma unroll
    for (int nt = 0; nt < 6; ++nt)
#pragma unroll
      for (int kt = 0; kt < 8; ++kt)
        bfrag[nt][kt] = *(const short8*)(whh + (size_t)(n0 + nt * 16) * 256 + kt * 32 + kq);
  }

  float bhr = 0.f, bhz = 0.f, bhn = 0.f, hprev = 0.f;
  if (tid < 256) { bhr = bhh[tid]; bhz = bhh[256 + tid]; bhn = bhh[512 + tid]; }

  // prologue: wait DMA + h init, then converge
  asm volatile("s_waitcnt vmcnt(0) lgkmcnt(0)\n\ts_barrier" ::: "memory");

  for (int t = 0; t < Sd; ++t) {
    const int rb = t & 1, wb = rb ^ 1;

    // preload this step's gi values (buffer stable since prev barrier B;
    // DMA landing for the group was guaranteed at t%8==7 of the prev step)
    float gl0 = 0.f, gl1 = 0.f, gl2 = 0.f;
    if (tid < 256) {
      const float* gl = gi_lds[(t >> 3) & 1][t & 7];
      gl0 = gl[tid]; gl1 = gl[256 + tid]; gl2 = gl[512 + tid];
    }

    // --- MFMA phase (all 8 waves, 48 MFMAs each) ---
    f32x4 acc[6];
#pragma unroll
    for (int nt = 0; nt < 6; ++nt) acc[nt] = (f32x4){0.f, 0.f, 0.f, 0.f};
#pragma unroll
    for (int kt = 0; kt < 8; ++kt) {
      // broadcast h chunk; A rows 0-15 all replicate h (only D row 0 is read)
      short8 av = *(const short8*)(&h_bf[rb][kt * 32 + kq]);
#pragma unroll
      for (int nt = 0; nt < 6; ++nt)
        acc[nt] = __builtin_amdgcn_mfma_f32_16x16x32_bf16(av, bfrag[nt][kt], acc[nt], 0, 0, 0);
      // pin issue order: {1 ds_read, 6 independent MFMAs} per kt group so a
      // wave never sits on a dependent-chain stall while other chains are
      // ready (in-order issue hazard at 2 waves/SIMD).
      __builtin_amdgcn_sched_group_barrier(0x100, 1, 0);  // DS_READ x1
      __builtin_amdgcn_sched_group_barrier(0x008, 6, 0);  // MFMA x6
    }
    if (lane < 16) {
#pragma unroll
      for (int nt = 0; nt < 6; ++nt) gh[w * 96 + nt * 16 + lane] = acc[nt][0];
    }
    asm volatile("s_waitcnt lgkmcnt(0)\n\ts_barrier" ::: "memory");   // barrier A: gh visible

    if (tid < 256) {
      // --- elementwise waves 0-3: one h value per lane ---
      float rr = fsigm(gl0 + gh[tid] + bhr);
      float zz = fsigm(gl1 + gh[256 + tid] + bhz);
      float nn = ftanh(gl2 + rr * (gh[512 + tid] + bhn));
      float hn = (1.f - zz) * nn + zz * hprev;
      hprev = hn;
      h_bf[wb][tid] = __float2bfloat16(hn);
      stg32[(t >> 3) & 1][t & 7][tid] = hn;
    } else if ((t & 7) == 0) {
      // --- memory waves 4-7: overlapped with elementwise ---
      if (t + 8 < Sd) {
        // prefetch tile t+8 into the buffer NOT read this group
        const int buf = ((t >> 3) + 1) & 1;
#pragma unroll
        for (int i = 0; i < 6; ++i) {
          int idx = (tid - 256) + i * 256;   // 0..1535
          int u = idx / 192;
          int c4 = (idx - u * 192) * 4;
          int s = dir ? (255 - (t + 8 + u)) : (t + 8 + u);
          const float* g = gi + (size_t)(((b << 8) + s) * 768 + c4);
          __builtin_amdgcn_global_load_lds(
              (const __attribute__((address_space(1))) unsigned int*)g,
              (__attribute__((address_space(3))) unsigned int*)&gi_lds[buf][u][c4], 16, 0, 0);
        }
      }
      if (t >= 8) {
        // store the group finished last step (steps t-8..t-1)
        const int base = t - 8;
        const int gp = ((t >> 3) - 1) & 1;
        const int d = tid - 256;
#pragma unroll
        for (int u = 0; u < 8; ++u) {
          int sg = dir ? (255 - (base + u)) : (base + u);
          size_t rowg = (size_t)((b << 8) + sg);
          int col = dir ? (256 + d) : d;
          float v = stg32[gp][u][d];
          sent_rep[rowg * 512 + col] = v;
          sent_rep_bf[rowg * 512 + col] = __float2bfloat16(v);
        }
      }
    }
    // memory waves: guarantee the NEXT group's tile (DMA'd at t-7) has landed
    // before barrier B of the group's last step -> step-top preload is safe.
    if (w >= 4 && (t & 7) == 7)
      asm volatile("s_waitcnt vmcnt(0)" ::: "memory");
    asm volatile("s_waitcnt lgkmcnt(0)\n\ts_barrier" ::: "memory");   // barrier B: h visible
  }

  // epilogue: store last group (31, in stg32[1]) + final hidden
  if (w >= 4) {
    const int base = 248, d = tid - 256;
#pragma unroll
    for (int u = 0; u < 8; ++u) {
      int sg = dir ? (255 - (base + u)) : (base + u);
      size_t rowg = (size_t)((b << 8) + sg);
      int col = dir ? (256 + d) : d;
      float v = stg32[1][u][d];
      sent_rep[rowg * 512 + col] = v;
      sent_rep_bf[rowg * 512 + col] = __float2bfloat16(v);
    }
  } else {
    (dir ? hT_b : hT_f)[b * 256 + tid] = hprev;
  }
}

// ---------------------------------------------------------------------------
// 5. doc_vec per torch view(B,2H) on stacked [2,B,H]. grid 32, block 512.
__global__ void docvec_kernel(const float* __restrict__ hTf, const float* __restrict__ hTb,
                              __hip_bfloat16* __restrict__ dv) {
  int b = blockIdx.x, jj = threadIdx.x;
  int idx = b * 512 + jj;
  int dsel = idx >> 13;            // /8192
  int rem = idx & 8191;
  int bp = rem >> 8, hp = rem & 255;
  float v = (dsel ? hTb : hTf)[bp * Hd + hp];
  dv[idx] = __float2bfloat16(v);
}

// 6. topic_mat via boundary differencing. grid 512 (b*16+t), block 256.
__global__ void topic_kernel(const int* __restrict__ tse, const float* __restrict__ sent_rep,
                             __hip_bfloat16* __restrict__ topic_bf) {
  int bt = blockIdx.x;
  int b = bt >> 4;
  int st = tse[bt * 2], en = tse[bt * 2 + 1];   // 1-indexed
  int dd = threadIdx.x;
  auto pad = [&](int i, int col) -> float {
    if (i < 1 || i > Sd) return 0.f;
    return sent_rep[((size_t)((b << 8) + (i - 1))) * 512 + col];
  };
  float fwd = pad(en, dd) - pad(st - 1, dd);
  float bwd = pad(st, Hd + dd) - pad(en + 1, Hd + dd);
  topic_bf[(size_t)bt * 512 + dd] = __float2bfloat16(fwd);
  topic_bf[(size_t)bt * 512 + Hd + dd] = __float2bfloat16(bwd);
}

// ---------------------------------------------------------------------------
// 7. attention scores. grid 8192 (b*256+s), block 256.
// QU rows are 1280 wide (Q = cols 0..1023); PD/RT rows 1280 (P/R = cols 0..1023).
__global__ void scores_kernel(const float* __restrict__ PD, const float* __restrict__ RT,
                              const float* __restrict__ QU, const float* __restrict__ v_att,
                              const int* __restrict__ tse,
                              float* __restrict__ dsc, float* __restrict__ tsc) {
  int r = blockIdx.x;
  int b = r >> 8, s = r & 255;
  int tid = threadIdx.x;
  int tsel = Td - 1;
  for (int t = 0; t < Td; ++t) {
    if (tse[(b * Td + t) * 2 + 1] >= s + 1) { tsel = t; break; }
  }
  const float* q = QU + (size_t)r * 1280;
  const float* p = PD + (size_t)b * 1280;
  const float* rr = RT + (size_t)(b * Td + tsel) * 1280;
  float accd = 0.f, acct = 0.f;
  for (int n = tid; n < 1024; n += 256) {
    float qv = q[n];
    float vv = v_att[n];
    accd += ftanh(p[n] + qv) * vv;
    acct += ftanh(rr[n] + qv) * vv;
  }
  __shared__ float s1[256], s2[256];
  s1[tid] = accd; s2[tid] = acct;
  __syncthreads();
  for (int off = 128; off > 0; off >>= 1) {
    if (tid < off) { s1[tid] += s1[tid + off]; s2[tid] += s2[tid + off]; }
    __syncthreads();
  }
  if (tid == 0) { dsc[r] = s1[0]; tsc[r] = s2[0]; }
}

// 8. softmax over s per batch (both score sets). grid 32, block 256.
__global__ void softmax_kernel(const float* __restrict__ dsc, const float* __restrict__ tsc,
                               float* __restrict__ dw, float* __restrict__ tw) {
  int b = blockIdx.x, s = threadIdx.x;
  __shared__ float red[256];
  for (int which = 0; which < 2; ++which) {
    const float* src = which ? tsc : dsc;
    float v = src[b * Sd + s];
    red[s] = v; __syncthreads();
    for (int off = 128; off > 0; off >>= 1) {
      if (s < off) red[s] = fmaxf(red[s], red[s + off]);
      __syncthreads();
    }
    float m = red[0]; __syncthreads();
    float e = __expf(v - m);
    red[s] = e; __syncthreads();
    for (int off = 128; off > 0; off >>= 1) {
      if (s < off) red[s] += red[s + off];
      __syncthreads();
    }
    float sum = red[0]; __syncthreads();
    (which ? tw : dw)[b * Sd + s] = e / sum;
  }
}

// 9. final head. grid 8192, block 256. OUTPUT IS FP32.
// U = QU cols 1024..1279; dvd = PD cols 1024..1279; tvd = RT cols 1024..1279.
__global__ void final_kernel(const float* __restrict__ QU, const float* __restrict__ PD,
                             const float* __restrict__ RT, const float* __restrict__ dw,
                             const float* __restrict__ tw, const float* __restrict__ b_dna,
                             const float* __restrict__ w_out,
                             const float* __restrict__ b_out,
                             const int* __restrict__ tse, float* __restrict__ out) {
  int r = blockIdx.x;
  int b = r >> 8, s = r & 255;
  int dd = threadIdx.x;
  int tsel = Td - 1;
  for (int t = 0; t < Td; ++t) {
    if (tse[(b * Td + t) * 2 + 1] >= s + 1) { tsel = t; break; }
  }
  float wdv = dw[b * Sd + s], wtv = tw[b * Sd + s];
  float x = QU[(size_t)r * 1280 + 1024 + dd] + wdv * PD[(size_t)b * 1280 + 1024 + dd] +
            wtv * RT[(size_t)(b * Td + tsel) * 1280 + 1024 + dd] + b_dna[dd];
  x = fmaxf(x, 0.f);
  float term = x * w_out[dd];
  __shared__ float red[256];
  red[dd] = term; __syncthreads();
  for (int off = 128; off > 0; off >>= 1) {
    if (dd < off) red[dd] += red[dd + off];
    __syncthreads();
  }
  if (dd == 0) out[r] = red[0] + b_out[0];
}

// ---------------------------------------------------------------------------
static void launch_gemm(const __hip_bfloat16* A, int lda, const __hip_bfloat16* W, int ldw,
                        float* C, int ldc, int M, int N, int K,
                        const float* bias, hipStream_t stream) {
  dim3 grid((M + 63) / 64, N / 64);
  gemm_xwt_kernel<<<grid, 256, 0, stream>>>(A, lda, W, ldw, C, ldc, M, N, K, bias);
}

extern "C" void kernel_launch(void* const* d_in, const int* in_sizes, int n_in,
                              void* d_out, int out_size, void* d_ws, size_t ws_size,
                              hipStream_t stream) {
  const int* word_ids = (const int*)d_in[0];
  const int* tse      = (const int*)d_in[1];
  const float* emb   = (const float*)d_in[2];
  const float* wih_f = (const float*)d_in[3];
  const float* whh_f = (const float*)d_in[4];
  const float* bih_f = (const float*)d_in[5];
  const float* bhh_f = (const float*)d_in[6];
  const float* wih_b = (const float*)d_in[7];
  const float* whh_b = (const float*)d_in[8];
  const float* bih_b = (const float*)d_in[9];
  const float* bhh_b = (const float*)d_in[10];
  const float* w_att = (const float*)d_in[11];
  const float* v_att = (const float*)d_in[12];
  const float* w_dna = (const float*)d_in[13];
  const float* b_dna = (const float*)d_in[14];
  const float* w_out = (const float*)d_in[15];
  const float* b_out = (const float*)d_in[16];
  float* out = (float*)d_out;
  char* ws = (char*)d_ws;

  const int M = Bd * Sd;  // 8192

  // workspace layout (bytes)
  size_t off = 0;
  auto alloc = [&](size_t sz) { size_t o = off; off += (sz + 255) & ~(size_t)255; return o; };
  size_t o_svbf   = alloc((size_t)M * EP * 2);          // A_pad bf16 [8192,320]
  size_t o_wpadf  = alloc((size_t)768 * EP * 2);
  size_t o_wpadb  = alloc((size_t)768 * EP * 2);
  size_t o_whhbf  = alloc((size_t)768 * Hd * 2 * 2);    // whh f+b bf16
  size_t o_wpack1 = alloc((size_t)1280 * 512 * 2);      // [W_att[:512];W_dna[512:]] ^T bf16
  size_t o_wpack2 = alloc((size_t)1280 * 512 * 2);      // [W_att[512:];W_dna[:512]] ^T bf16
  size_t o_hTf    = alloc((size_t)Bd * Hd * 4);
  size_t o_hTb    = alloc((size_t)Bd * Hd * 4);
  size_t o_dvbf   = alloc((size_t)Bd * 512 * 2);        // doc_vec bf16
  size_t o_topbf  = alloc((size_t)Bd * Td * 512 * 2);   // topic_mat bf16
  size_t o_PD     = alloc((size_t)Bd * 1280 * 4);       // [P | dvd]
  size_t o_RT     = alloc((size_t)Bd * Td * 1280 * 4);  // [R | tvd]
  size_t o_dsc    = alloc((size_t)Bd * Sd * 4);
  size_t o_tsc    = alloc((size_t)Bd * Sd * 4);
  size_t o_dw     = alloc((size_t)Bd * Sd * 4);
  size_t o_tw     = alloc((size_t)Bd * Sd * 4);
  size_t o_srep32 = alloc((size_t)M * 512 * 4);         // sent_rep fp32
  size_t o_srepbf = alloc((size_t)M * 512 * 2);         // sent_rep bf16
  size_t o_gif    = alloc((size_t)M * 768 * 4);         // gi fwd fp32
  size_t o_gib    = alloc((size_t)M * 768 * 4);         // gi bwd fp32
  // QU [8192,1280] f32 overlays the dead gi region after the GRU
  size_t o_QU = o_gif;
  (void)ws_size;

  __hip_bfloat16* svbf   = (__hip_bfloat16*)(ws + o_svbf);
  __hip_bfloat16* wpadf  = (__hip_bfloat16*)(ws + o_wpadf);
  __hip_bfloat16* wpadb  = (__hip_bfloat16*)(ws + o_wpadb);
  __hip_bfloat16* whhbf_f = (__hip_bfloat16*)(ws + o_whhbf);
  __hip_bfloat16* whhbf_b = whhbf_f + 768 * Hd;
  __hip_bfloat16* wpack1 = (__hip_bfloat16*)(ws + o_wpack1);
  __hip_bfloat16* wpack2 = (__hip_bfloat16*)(ws + o_wpack2);
  float* hTf = (float*)(ws + o_hTf);
  float* hTb = (float*)(ws + o_hTb);
  __hip_bfloat16* dvbf  = (__hip_bfloat16*)(ws + o_dvbf);
  __hip_bfloat16* topbf = (__hip_bfloat16*)(ws + o_topbf);
  float* PD  = (float*)(ws + o_PD);
  float* RT  = (float*)(ws + o_RT);
  float* dsc = (float*)(ws + o_dsc);
  float* tsc = (float*)(ws + o_tsc);
  float* dw  = (float*)(ws + o_dw);
  float* tw  = (float*)(ws + o_tw);
  float* srep32 = (float*)(ws + o_srep32);
  __hip_bfloat16* srepbf = (__hip_bfloat16*)(ws + o_srepbf);
  float* gif = (float*)(ws + o_gif);
  float* gib = (float*)(ws + o_gib);
  float* QU  = (float*)(ws + o_QU);

  // 1. sentence means -> padded bf16 activations
  sent_means_kernel<<<M, EP, 0, stream>>>(word_ids, emb, svbf);
  // 2. fused GRU weight prep
  prep1_kernel<<<1728, 512, 0, stream>>>(wih_f, wih_b, whh_f, whh_b,
                                         wpadf, wpadb, whhbf_f, whhbf_b);
  // 3. input projections gi = sv @ Wih^T + bih
  launch_gemm(svbf, EP, wpadf, EP, gif, 768, M, 768, EP, bih_f, stream);
  launch_gemm(svbf, EP, wpadb, EP, gib, 768, M, 768, EP, bih_b, stream);
  // 4. GRU recurrence + fused att/dna weight packing on idle CUs
  gru_mfma_kernel<<<384, 512, 0, stream>>>(gif, gib, whhbf_f, whhbf_b, bhh_f, bhh_b,
                                           srep32, srepbf, hTf, hTb,
                                           w_att, w_dna, wpack1, wpack2);
  // 5/6. doc_vec + topic_mat
  docvec_kernel<<<Bd, 512, 0, stream>>>(hTf, hTb, dvbf);
  topic_kernel<<<Bd * Td, 256, 0, stream>>>(tse, srep32, topbf);
  // 7. merged attention/dense GEMMs
  launch_gemm(srepbf, 512, wpack2, 512, QU, 1280, M, 1280, 512, nullptr, stream);
  launch_gemm(dvbf, 512, wpack1, 512, PD, 1280, Bd, 1280, 512, nullptr, stream);
  launch_gemm(topbf, 512, wpack1, 512, RT, 1280, Bd * Td, 1280, 512, nullptr, stream);
  // 8. scores + softmax
  scores_kernel<<<M, 256, 0, stream>>>(PD, RT, QU, v_att, tse, dsc, tsc);
  softmax_kernel<<<Bd, 256, 0, stream>>>(dsc, tsc, dw, tw);
  // 9. fused dense head -> logits (fp32)
  final_kernel<<<M, 256, 0, stream>>>(QU, PD, RT, dw, tw, b_dna, w_out, b_out, tse, out);
}